// Round 8
// baseline (191.269 us; speedup 1.0000x reference)
//
#include <hip/hip_runtime.h>

// PositionalEncoder: out[k] = sum_j ((1 - j/J) - (k/d)*(1 - 2j/J)) * E[j,k]
// j = 1..J (row+1), k = 1..d (col+1). E row-major [J, D] fp32.
//
// R8 theory: reads cap at ~2.8 TB/s fabric throughput in R4 AND R7 despite
// different store paths / occupancy / sweep — suspect the per-CU VGPR
// writeback return path. Test: stream E with global_load_lds (direct
// TCC->LDS, no VGPR return), per-wave private double-buffered 8 KB row
// buffers, manual s_waitcnt vmcnt(8) via inline asm (+memory clobber so
// the compiler can't reorder/defeat it), no barrier in the K-loop.
// Consume from LDS via ds_read_b128 (LDS BW >> 2.8 TB/s, not limiting).
// Reduction tree unchanged (R5-proven): coalesced full-line ws stores,
// stage2 (64 blocks), stage3.

constexpr int D_COLS = 2048;
constexpr int J_ROWS = 16384;
constexpr int TB1 = 256;                    // 4 waves/block
constexpr int NB1 = 1024;                   // stage-1 blocks
constexpr int NWAVES = NB1 * (TB1 / 64);    // 4096 waves; 4 rows/wave
constexpr int NB2 = 64;                     // stage-2 blocks
constexpr int T2T3 = 512;

typedef float vf4 __attribute__((ext_vector_type(4)));

#define GLOBAL_AS __attribute__((address_space(1)))
#define LDS_AS    __attribute__((address_space(3)))
// Inline-asm waitcnt: immediate N, memory clobber pins ordering vs ds_read.
#define WAIT_VMCNT(N) asm volatile("s_waitcnt vmcnt(%0)" ::"n"(N) : "memory")

__global__ __launch_bounds__(TB1) void pe_stage1(const float* __restrict__ E,
                                                 float* __restrict__ ws) {
    // 4 waves x 2 buffers x 2048 floats = 64 KiB
    __shared__ float smem[4 * 2 * D_COLS];
    const int lane = threadIdx.x & 63;
    const int wv   = threadIdx.x >> 6;
    const int gw   = blockIdx.x * 4 + wv;        // global wave id, 0..4095
    const int bufA = wv * 2 * D_COLS;
    const int bufB = bufA + D_COLS;

    const float invJ = 1.0f / (float)J_ROWS;
    const float invD = 1.0f / (float)D_COLS;

    // Per-lane column constants and accumulators: chunk i covers cols
    // [i*256, i*256+256), lane L owns cols i*256 + L*4 + {0..3}.
    vf4 c[8], acc[8];
    #pragma unroll
    for (int i = 0; i < 8; ++i) {
        const int col = i * 256 + lane * 4;
        c[i].x = (float)(col + 1) * invD;
        c[i].y = (float)(col + 2) * invD;
        c[i].z = (float)(col + 3) * invD;
        c[i].w = (float)(col + 4) * invD;
        acc[i] = (vf4)0.f;
    }

    // Stage one full 8 KB row into LDS: 8 x global_load_lds width=16.
    // LDS dest is wave-uniform base; HW adds lane*16 (m104 contract), which
    // matches the global side's lane*4 floats exactly.
    auto issue_row = [&](int buf, int row) {
        const float* g = E + (size_t)row * D_COLS + lane * 4;
        #pragma unroll
        for (int i = 0; i < 8; ++i) {
            __builtin_amdgcn_global_load_lds(
                (const GLOBAL_AS void*)(g + i * 256),
                (LDS_AS void*)&smem[buf + i * 256],
                16, 0, 0);
        }
    };

    auto consume = [&](int buf, int row) {
        const float jf = (float)(row + 1);
        const float aa = fmaf(-jf, invJ, 1.0f);          // 1 - j/J
        const float bb = fmaf(-2.0f * jf, invJ, 1.0f);   // 1 - 2j/J
        #pragma unroll
        for (int i = 0; i < 8; ++i) {
            const vf4 e = *(const vf4*)&smem[buf + i * 256 + lane * 4];
            vf4 w;
            w.x = fmaf(-c[i].x, bb, aa);
            w.y = fmaf(-c[i].y, bb, aa);
            w.z = fmaf(-c[i].z, bb, aa);
            w.w = fmaf(-c[i].w, bb, aa);
            acc[i].x = fmaf(w.x, e.x, acc[i].x);
            acc[i].y = fmaf(w.y, e.y, acc[i].y);
            acc[i].z = fmaf(w.z, e.z, acc[i].z);
            acc[i].w = fmaf(w.w, e.w, acc[i].w);
        }
    };

    // Sweep row order: step s reads rows [s*4096, (s+1)*4096) grid-wide.
    // Double-buffered: one row's DMA always in flight during consume.
    issue_row(bufA, gw);                 //  8 outstanding
    issue_row(bufB, NWAVES + gw);        // 16 outstanding
    WAIT_VMCNT(8);                       // bufA ready
    consume(bufA, gw);
    issue_row(bufA, 2 * NWAVES + gw);
    WAIT_VMCNT(8);                       // bufB ready
    consume(bufB, NWAVES + gw);
    issue_row(bufB, 3 * NWAVES + gw);
    WAIT_VMCNT(8);                       // bufA ready
    consume(bufA, 2 * NWAVES + gw);
    WAIT_VMCNT(0);                       // bufB ready
    consume(bufB, 3 * NWAVES + gw);

    // Block-level combine through LDS (buffers are free now), then one
    // coalesced full-line row store (R5 lesson: never scatter to poisoned ws).
    #pragma unroll
    for (int i = 0; i < 8; ++i)
        *(vf4*)&smem[wv * 2 * D_COLS + i * 256 + lane * 4] = acc[i];
    __syncthreads();

    const int t = threadIdx.x;
    #pragma unroll
    for (int m = 0; m < 2; ++m) {
        const int col = m * 1024 + t * 4;          // 256 threads x 4 floats
        vf4 s = *(const vf4*)&smem[0 * 2 * D_COLS + col];
        s += *(const vf4*)&smem[1 * 2 * D_COLS + col];
        s += *(const vf4*)&smem[2 * 2 * D_COLS + col];
        s += *(const vf4*)&smem[3 * 2 * D_COLS + col];
        *(vf4*)&ws[(size_t)blockIdx.x * D_COLS + col] = s;
    }
}

// stage2: block b sums ws rows [16b, 16b+16) -> ws2[b][*]. All coalesced.
__global__ __launch_bounds__(T2T3) void pe_stage2(const float* __restrict__ ws,
                                                  float* __restrict__ ws2) {
    const int col0 = threadIdx.x * 4;
    const int b    = blockIdx.x;
    const float* base = ws + (size_t)(b * (NB1 / NB2)) * D_COLS + col0;
    vf4 acc = (vf4)0.f;
    #pragma unroll
    for (int r = 0; r < NB1 / NB2; ++r)
        acc += *(const vf4*)(base + (size_t)r * D_COLS);
    *(vf4*)(ws2 + (size_t)b * D_COLS + col0) = acc;
}

// stage3: thread k sums ws2[r][k], r=0..63 (L2-hot, 4-way ILP). Writes out.
__global__ __launch_bounds__(T2T3) void pe_stage3(const float* __restrict__ ws2,
                                                  float* __restrict__ out) {
    const int k = blockIdx.x * T2T3 + threadIdx.x;
    float s0 = 0.f, s1 = 0.f, s2 = 0.f, s3 = 0.f;
    #pragma unroll
    for (int r = 0; r < NB2; r += 4) {
        s0 += ws2[(size_t)(r + 0) * D_COLS + k];
        s1 += ws2[(size_t)(r + 1) * D_COLS + k];
        s2 += ws2[(size_t)(r + 2) * D_COLS + k];
        s3 += ws2[(size_t)(r + 3) * D_COLS + k];
    }
    out[k] = (s0 + s1) + (s2 + s3);
}

extern "C" void kernel_launch(void* const* d_in, const int* in_sizes, int n_in,
                              void* d_out, int out_size, void* d_ws, size_t ws_size,
                              hipStream_t stream) {
    const float* E = (const float*)d_in[0];
    float* out = (float*)d_out;
    float* ws  = (float*)d_ws;                          // 8 MiB partials
    float* ws2 = ws + (size_t)NB1 * D_COLS;             // +512 KB second level
    (void)in_sizes; (void)n_in; (void)out_size; (void)ws_size;

    pe_stage1<<<NB1, TB1, 0, stream>>>(E, ws);
    pe_stage2<<<NB2, T2T3, 0, stream>>>(ws, ws2);
    pe_stage3<<<D_COLS / T2T3, T2T3, 0, stream>>>(ws2, out);
}